// Round 6
// baseline (272.100 us; speedup 1.0000x reference)
//
#include <hip/hip_runtime.h>
#include <math.h>

typedef __bf16 bf16_t;
typedef __bf16 bf16x8 __attribute__((ext_vector_type(8)));
typedef __bf16 bf16x4 __attribute__((ext_vector_type(4)));
typedef float f32x4 __attribute__((ext_vector_type(4)));

#define MFMA16(a, b, c) __builtin_amdgcn_mfma_f32_16x16x32_bf16((a), (b), (c), 0, 0, 0)

constexpr int Bc = 2, Nc = 2048, Dc = 1024, Hc = 16, HDc = 64;
constexpr float C1 = 0.18033688011112042f;     // 0.125 * log2(e)
constexpr float LOG2E = 1.4426950408889634f;

// async global->LDS, 16B per lane; LDS base must be wave-uniform (HW adds lane*16)
__device__ __forceinline__ void glds16(const bf16_t* g, bf16_t* l) {
    __builtin_amdgcn_global_load_lds(
        (const __attribute__((address_space(1))) unsigned int*)g,
        (__attribute__((address_space(3))) unsigned int*)l, 16, 0, 0);
}

// ---------------------------------------------------------------------------
// Fused fp32->bf16 convert + pooling partial. 512 blocks x 8 rows.
__global__ __launch_bounds__(256) void prep_x(const float* __restrict__ x,
                                              bf16_t* __restrict__ Xb,
                                              float* __restrict__ pooled) {
    int row0 = blockIdx.x * 8;
    int b = row0 >> 11;
    int c = threadIdx.x * 4;
    float s0 = 0.f, s1 = 0.f, s2 = 0.f, s3 = 0.f;
#pragma unroll
    for (int rr = 0; rr < 8; ++rr) {
        size_t off = (size_t)(row0 + rr) * 1024 + c;
        float4 v = *(const float4*)(x + off);
        bf16x4 o = { (bf16_t)v.x, (bf16_t)v.y, (bf16_t)v.z, (bf16_t)v.w };
        *(bf16x4*)(Xb + off) = o;
        s0 += v.x; s1 += v.y; s2 += v.z; s3 += v.w;
    }
    atomicAdd(&pooled[b * 1024 + c + 0], s0);
    atomicAdd(&pooled[b * 1024 + c + 1], s1);
    atomicAdd(&pooled[b * 1024 + c + 2], s2);
    atomicAdd(&pooled[b * 1024 + c + 3], s3);
}

// ---------------------------------------------------------------------------
// Both weight transposes in one launch. grid (64,16).
__global__ __launch_bounds__(256) void tr64f(const float* __restrict__ w_qkv,
                                             const float* __restrict__ w_out,
                                             bf16_t* __restrict__ Wt,
                                             bf16_t* __restrict__ WoT) {
    __shared__ bf16_t tile[64 * 66];
    const float* src; bf16_t* dst; int C, cx;
    if (blockIdx.x < 48) { src = w_qkv; dst = Wt; C = 3072; cx = blockIdx.x; }
    else                 { src = w_out; dst = WoT; C = 1024; cx = blockIdx.x - 48; }
    const int R = 1024;
    int r0 = blockIdx.y * 64, c0 = cx * 64;
    int t = threadIdx.x;
    int cl = t & 63, rl = t >> 6;
#pragma unroll
    for (int p = 0; p < 16; ++p) {
        int r = p * 4 + rl;
        tile[r * 66 + cl] = (bf16_t)src[(size_t)(r0 + r) * C + c0 + cl];
    }
    __syncthreads();
#pragma unroll
    for (int p = 0; p < 16; ++p) {
        int r = p * 4 + rl;
        dst[(size_t)(c0 + r) * R + r0 + cl] = tile[cl * 66 + r];
    }
}

// ---------------------------------------------------------------------------
// Gate MLP stage 1, parallel: one block per (b, j). hacc[b] += silu(h_j)*w_fg2[j]
__global__ __launch_bounds__(256) void gate1(const float* __restrict__ pooled,
                                             const float* __restrict__ w_fg1,
                                             const float* __restrict__ b_fg1,
                                             const float* __restrict__ w_fg2,
                                             float* __restrict__ hacc) {
    int b = blockIdx.x >> 8, j = blockIdx.x & 255;
    int t = threadIdx.x;
    float p = 0.f;
#pragma unroll
    for (int i = 0; i < 4; ++i) {
        int d = t * 4 + i;
        p += pooled[b * 1024 + d] * w_fg1[d * 256 + j];
    }
#pragma unroll
    for (int off = 32; off > 0; off >>= 1) p += __shfl_down(p, off);
    __shared__ float red[4];
    if ((t & 63) == 0) red[t >> 6] = p;
    __syncthreads();
    if (t == 0) {
        float hj = (red[0] + red[1] + red[2] + red[3]) * (1.0f / 2048.0f) + b_fg1[j];
        hj = hj / (1.0f + __expf(-hj)); // silu
        atomicAdd(&hacc[b], hj * w_fg2[j]);
    }
}

// ---------------------------------------------------------------------------
__global__ __launch_bounds__(256) void covbias_k(const float* __restrict__ coverage,
                                                 const float* __restrict__ w_ce1,
                                                 const float* __restrict__ b_ce1,
                                                 const float* __restrict__ w_ce2,
                                                 const float* __restrict__ b_ce2,
                                                 const float* __restrict__ hacc,
                                                 const float* __restrict__ b_fg2,
                                                 float* __restrict__ biasbuf) {
    int t = threadIdx.x;
    int h = t & 15;
    int gn = blockIdx.x * 16 + (t >> 4);
    int b = gn >> 11, n = gn & 2047;
    float g = 1.0f / (1.0f + __expf(-(hacc[b] + b_fg2[0])));
    float c = coverage[gn];
    float acc = b_ce2[h];
    for (int j = 0; j < 256; ++j) {
        float tv = c * w_ce1[j] + b_ce1[j];
        tv = tv / (1.0f + __expf(-tv));
        acc += tv * w_ce2[j * 16 + h];
    }
    biasbuf[((size_t)b * 16 + h) * 2048 + n] = LOG2E * g * acc;
}

// ---------------------------------------------------------------------------
// QKV GEMM, transposed orientation. Vt written KEY-PERMUTED: within each
// 32-key group, key 16b+4q+o stored at position 8q+4b+o (so attn PV B-frags
// are contiguous 16B per lane).
__global__ __launch_bounds__(256) void qkv_gemm(const bf16_t* __restrict__ Xb,
                                                const bf16_t* __restrict__ Wt,
                                                bf16_t* __restrict__ Q,
                                                bf16_t* __restrict__ Kb,
                                                bf16_t* __restrict__ Vt) {
    __shared__ __align__(16) bf16_t At[128 * 32];
    __shared__ __align__(16) bf16_t Bt[128 * 32];
    int t = threadIdx.x, w = t >> 6, lane = t & 63;
    int l16 = lane & 15, quad = lane >> 4;
    int wm = w & 1, wx = w >> 1;
    int m0 = blockIdx.x * 128;
    int n0 = blockIdx.y * 128;
    f32x4 acc[4][4] = {};
    int sw = (l16 >> 2) & 3;

    for (int k0 = 0; k0 < 1024; k0 += 32) {
#pragma unroll
        for (int i = 0; i < 2; ++i) {
            int fb = i * 4096 + w * 1024;
            int f = fb + lane * 16;
            int row = f >> 6;
            int ch = (f >> 4) & 3;
            int sc = ch ^ ((row >> 2) & 3);
            glds16(Wt + (size_t)(n0 + row) * 1024 + k0 + sc * 8, At + (fb >> 1));
            glds16(Xb + (size_t)(m0 + row) * 1024 + k0 + sc * 8, Bt + (fb >> 1));
        }
        __syncthreads();
        bf16x8 afr[4], bfr[4];
#pragma unroll
        for (int mi = 0; mi < 4; ++mi)
            afr[mi] = *(const bf16x8*)(At + (wm * 64 + mi * 16 + l16) * 32 + ((quad ^ sw) * 8));
#pragma unroll
        for (int ni = 0; ni < 4; ++ni)
            bfr[ni] = *(const bf16x8*)(Bt + (wx * 64 + ni * 16 + l16) * 32 + ((quad ^ sw) * 8));
#pragma unroll
        for (int mi = 0; mi < 4; ++mi)
#pragma unroll
            for (int ni = 0; ni < 4; ++ni)
                acc[mi][ni] = MFMA16(afr[mi], bfr[ni], acc[mi][ni]);
        __syncthreads();
    }

    int sec = n0 >> 10;
#pragma unroll
    for (int mi = 0; mi < 4; ++mi) {
        int gc = n0 + wm * 64 + mi * 16 + quad * 4;
        int dcol = gc & 1023;
        int h = dcol >> 6, hd = dcol & 63;
#pragma unroll
        for (int ni = 0; ni < 4; ++ni) {
            int gx = m0 + wx * 64 + ni * 16 + l16;
            int b = gx >> 11, n = gx & 2047;
            size_t bh = (size_t)(b * 16 + h);
            if (sec == 2) {
                // key permutation: pos = 8q + 4b + o for key 16b + 4q + o
                int np = (n & ~31) + ((n >> 2) & 3) * 8 + ((n >> 4) & 1) * 4 + (n & 3);
#pragma unroll
                for (int r = 0; r < 4; ++r)
                    Vt[(bh * 64 + hd + r) * 2048 + np] = (bf16_t)acc[mi][ni][r];
            } else {
                bf16x4 pk = { (bf16_t)acc[mi][ni][0], (bf16_t)acc[mi][ni][1],
                              (bf16_t)acc[mi][ni][2], (bf16_t)acc[mi][ni][3] };
                bf16_t* dst = (sec == 0 ? Q : Kb);
                *(bf16x4*)(dst + (bh * 2048 + n) * 64 + hd) = pk;
            }
        }
    }
}

// ---------------------------------------------------------------------------
// Flash attention v4: 4 waves x 32 q = 128 q/block, grid (16,32) = 512 blocks.
// S^T = K.Q^T, no-max exp2 softmax, double-buffered swizzled K+V LDS,
// key-permuted V -> b128 V-frags, row sums via ones-MFMA.
__global__ __launch_bounds__(256) void attn_k(const bf16_t* __restrict__ Q,
                                              const bf16_t* __restrict__ Kb,
                                              const bf16_t* __restrict__ Vt,
                                              const float* __restrict__ biasbuf,
                                              bf16_t* __restrict__ O) {
    __shared__ __align__(16) bf16_t kbuf[2][64 * 64];
    __shared__ __align__(16) bf16_t vbuf[2][64 * 64];
    int t = threadIdx.x, w = t >> 6, lane = t & 63;
    int l16 = lane & 15, quad = lane >> 4;
    int bh = blockIdx.y;
    int b = bh >> 4, h = bh & 15;
    int qa = blockIdx.x * 128 + w * 32;
    const bf16_t* Qh = Q + (size_t)bh * 2048 * 64;
    const bf16_t* Kh = Kb + (size_t)bh * 2048 * 64;
    const bf16_t* Vh = Vt + (size_t)bh * 64 * 2048;
    const float* bih = biasbuf + (size_t)bh * 2048;

    int fb0 = w * 2048, fb1 = fb0 + 1024;
    int f0 = fb0 + lane * 16, f1 = fb1 + lane * 16;
    int krow0 = f0 >> 7, kch0 = ((f0 >> 4) & 7) ^ (krow0 & 7);
    int krow1 = f1 >> 7, kch1 = ((f1 >> 4) & 7) ^ (krow1 & 7);

    bf16x8 qf[2][2];
#pragma unroll
    for (int g = 0; g < 2; ++g)
#pragma unroll
        for (int dh = 0; dh < 2; ++dh)
            qf[g][dh] = *(const bf16x8*)(Qh + (size_t)(qa + g * 16 + l16) * 64 + dh * 32 + quad * 8);

    f32x4 o[2][4] = {};
    f32x4 osum[2] = {};
    const f32x4 zero = { 0.f, 0.f, 0.f, 0.f };
    int swl = l16 & 7;
    bf16x8 ones;
#pragma unroll
    for (int i = 0; i < 8; ++i) ones[i] = (bf16_t)1.0f;

    {
        glds16(Kh + (size_t)krow0 * 64 + kch0 * 8, &kbuf[0][fb0 >> 1]);
        glds16(Kh + (size_t)krow1 * 64 + kch1 * 8, &kbuf[0][fb1 >> 1]);
        glds16(Vh + (size_t)krow0 * 2048 + kch0 * 8, &vbuf[0][fb0 >> 1]);
        glds16(Vh + (size_t)krow1 * 2048 + kch1 * 8, &vbuf[0][fb1 >> 1]);
    }

    for (int it = 0; it < 32; ++it) {
        int j0 = it * 64, sel = it & 1;
        __syncthreads();
        if (it + 1 < 32) {
            int jn = j0 + 64, sn = sel ^ 1;
            glds16(Kh + (size_t)(jn + krow0) * 64 + kch0 * 8, &kbuf[sn][fb0 >> 1]);
            glds16(Kh + (size_t)(jn + krow1) * 64 + kch1 * 8, &kbuf[sn][fb1 >> 1]);
            glds16(Vh + (size_t)krow0 * 2048 + jn + kch0 * 8, &vbuf[sn][fb0 >> 1]);
            glds16(Vh + (size_t)krow1 * 2048 + jn + kch1 * 8, &vbuf[sn][fb1 >> 1]);
        }
        const bf16_t* kb = kbuf[sel];
        const bf16_t* vb = vbuf[sel];

        float4 bias[4];
#pragma unroll
        for (int kt = 0; kt < 4; ++kt)
            bias[kt] = *(const float4*)(bih + j0 + kt * 16 + quad * 4);

        f32x4 s[4][2];
#pragma unroll
        for (int kt = 0; kt < 4; ++kt) {
            bf16x8 kf0 = *(const bf16x8*)(kb + (kt * 16 + l16) * 64 + ((quad ^ swl) * 8));
            bf16x8 kf1 = *(const bf16x8*)(kb + (kt * 16 + l16) * 64 + (((4 + quad) ^ swl) * 8));
#pragma unroll
            for (int g = 0; g < 2; ++g) {
                s[kt][g] = MFMA16(kf0, qf[g][0], zero);
                s[kt][g] = MFMA16(kf1, qf[g][1], s[kt][g]);
            }
        }

#pragma unroll
        for (int kt = 0; kt < 4; ++kt) {
            const float* bp = (const float*)&bias[kt];
#pragma unroll
            for (int g = 0; g < 2; ++g)
#pragma unroll
                for (int r = 0; r < 4; ++r)
                    s[kt][g][r] = __builtin_amdgcn_exp2f(s[kt][g][r] * C1 + bp[r]);
        }

        // pack P A-frags (key perm: k=quad*8+j -> key=pv*32+16*(j>>2)+quad*4+(j&3))
        bf16x8 pf[2][2];
#pragma unroll
        for (int g = 0; g < 2; ++g)
#pragma unroll
            for (int pv = 0; pv < 2; ++pv) {
                bf16x8 tmp;
#pragma unroll
                for (int i = 0; i < 4; ++i) {
                    tmp[i]     = (bf16_t)s[2 * pv][g][i];
                    tmp[i + 4] = (bf16_t)s[2 * pv + 1][g][i];
                }
                pf[g][pv] = tmp;
            }

        // PV: V stored key-permuted, so lane's 8 keys are one b128
#pragma unroll
        for (int dt = 0; dt < 4; ++dt) {
            const bf16_t* vrow = vb + (dt * 16 + l16) * 64;
#pragma unroll
            for (int pv = 0; pv < 2; ++pv) {
                bf16x8 vf = *(const bf16x8*)(vrow + (((pv * 4 + quad) ^ swl) * 8));
#pragma unroll
                for (int g = 0; g < 2; ++g)
                    o[g][dt] = MFMA16(pf[g][pv], vf, o[g][dt]);
            }
        }
        // row sums via ones-MFMA (lands in same C-layout rows as o)
#pragma unroll
        for (int g = 0; g < 2; ++g) {
            osum[g] = MFMA16(pf[g][0], ones, osum[g]);
            osum[g] = MFMA16(pf[g][1], ones, osum[g]);
        }
    }

#pragma unroll
    for (int g = 0; g < 2; ++g) {
        float rinv[4];
#pragma unroll
        for (int r = 0; r < 4; ++r) rinv[r] = 1.0f / osum[g][r];
#pragma unroll
        for (int dt = 0; dt < 4; ++dt)
#pragma unroll
            for (int r = 0; r < 4; ++r) {
                int row = qa + g * 16 + quad * 4 + r;
                O[(size_t)(b * 2048 + row) * 1024 + h * 64 + dt * 16 + l16] =
                    (bf16_t)(o[g][dt][r] * rinv[r]);
            }
    }
}

// ---------------------------------------------------------------------------
// Output GEMM: tile 64(outcols) x 128(xrows), grid (32,16)=512 blocks.
__global__ __launch_bounds__(256) void out_gemm(const bf16_t* __restrict__ A,
                                                const bf16_t* __restrict__ Wt,
                                                const float* __restrict__ bias,
                                                float* __restrict__ Cout) {
    __shared__ __align__(16) bf16_t At[64 * 32];   // Wt rows (outcols)
    __shared__ __align__(16) bf16_t Bt[128 * 32];  // O rows
    int t = threadIdx.x, w = t >> 6, lane = t & 63;
    int l16 = lane & 15, quad = lane >> 4;
    int wm = w & 1, wx = w >> 1;
    int m0 = blockIdx.x * 128;   // xrows
    int n0 = blockIdx.y * 64;    // outcols
    f32x4 acc[2][4] = {};
    int sw = (l16 >> 2) & 3;

    for (int k0 = 0; k0 < 1024; k0 += 32) {
        {
            // At: 4KB, each wave 1KB
            int fb = w * 1024;
            int f = fb + lane * 16;
            int row = f >> 6;
            int ch = (f >> 4) & 3;
            int sc = ch ^ ((row >> 2) & 3);
            glds16(Wt + (size_t)(n0 + row) * 1024 + k0 + sc * 8, At + (fb >> 1));
        }
#pragma unroll
        for (int i = 0; i < 2; ++i) {
            // Bt: 8KB, each wave 2KB
            int fb = w * 2048 + i * 1024;
            int f = fb + lane * 16;
            int row = f >> 6;
            int ch = (f >> 4) & 3;
            int sc = ch ^ ((row >> 2) & 3);
            glds16(A + (size_t)(m0 + row) * 1024 + k0 + sc * 8, Bt + (fb >> 1));
        }
        __syncthreads();
        bf16x8 afr[2], bfr[4];
#pragma unroll
        for (int mi = 0; mi < 2; ++mi)
            afr[mi] = *(const bf16x8*)(At + (wm * 32 + mi * 16 + l16) * 32 + ((quad ^ sw) * 8));
#pragma unroll
        for (int ni = 0; ni < 4; ++ni)
            bfr[ni] = *(const bf16x8*)(Bt + (wx * 64 + ni * 16 + l16) * 32 + ((quad ^ sw) * 8));
#pragma unroll
        for (int mi = 0; mi < 2; ++mi)
#pragma unroll
            for (int ni = 0; ni < 4; ++ni)
                acc[mi][ni] = MFMA16(afr[mi], bfr[ni], acc[mi][ni]);
        __syncthreads();
    }

#pragma unroll
    for (int mi = 0; mi < 2; ++mi) {
        int gc = n0 + wm * 32 + mi * 16 + quad * 4;
        float4 bv = *(const float4*)(bias + gc);
#pragma unroll
        for (int ni = 0; ni < 4; ++ni) {
            int gx = m0 + wx * 64 + ni * 16 + l16;
            float4 ov = { acc[mi][ni][0] + bv.x, acc[mi][ni][1] + bv.y,
                          acc[mi][ni][2] + bv.z, acc[mi][ni][3] + bv.w };
            *(float4*)(Cout + (size_t)gx * 1024 + gc) = ov;
        }
    }
}

// ---------------------------------------------------------------------------
extern "C" void kernel_launch(void* const* d_in, const int* in_sizes, int n_in,
                              void* d_out, int out_size, void* d_ws, size_t ws_size,
                              hipStream_t stream) {
    const float* x     = (const float*)d_in[0];
    const float* cov   = (const float*)d_in[1];
    const float* w_qkv = (const float*)d_in[2];
    const float* w_out = (const float*)d_in[3];
    const float* b_out = (const float*)d_in[4];
    const float* w_ce1 = (const float*)d_in[5];
    const float* b_ce1 = (const float*)d_in[6];
    const float* w_ce2 = (const float*)d_in[7];
    const float* b_ce2 = (const float*)d_in[8];
    const float* w_fg1 = (const float*)d_in[9];
    const float* b_fg1 = (const float*)d_in[10];
    const float* w_fg2 = (const float*)d_in[11];
    const float* b_fg2 = (const float*)d_in[12];

    char* ws = (char*)d_ws;
    bf16_t* Wt     = (bf16_t*)(ws);              // 3072x1024
    bf16_t* WoT    = (bf16_t*)(ws + 6291456);    // 1024x1024
    bf16_t* Xb     = (bf16_t*)(ws + 8388608);    // 4096x1024
    bf16_t* Qb     = (bf16_t*)(ws + 16777216);   // (2,16,2048,64)
    bf16_t* Kbb    = (bf16_t*)(ws + 25165824);   // (2,16,2048,64)
    bf16_t* Vt     = (bf16_t*)(ws + 33554432);   // (2,16,64,2048) key-permuted
    bf16_t* Ob     = (bf16_t*)(ws + 41943040);   // (4096,1024)
    float*  pooled = (float*)(ws + 50331648);    // 2x1024 f32
    float*  hacc   = (float*)(ws + 50339840);    // 2 f32
    float*  biasb  = (float*)(ws + 50340096);    // 2x16x2048 f32

    hipMemsetAsync(pooled, 0, 8192 + 256, stream);  // pooled + hacc
    prep_x<<<512, 256, 0, stream>>>(x, Xb, pooled);
    tr64f<<<dim3(64, 16), 256, 0, stream>>>(w_qkv, w_out, Wt, WoT);
    gate1<<<512, 256, 0, stream>>>(pooled, w_fg1, b_fg1, w_fg2, hacc);
    covbias_k<<<256, 256, 0, stream>>>(cov, w_ce1, b_ce1, w_ce2, b_ce2, hacc, b_fg2, biasb);
    qkv_gemm<<<dim3(32, 24), 256, 0, stream>>>(Xb, Wt, Qb, Kbb, Vt);
    attn_k<<<dim3(16, 32), 256, 0, stream>>>(Qb, Kbb, Vt, biasb, Ob);
    out_gemm<<<dim3(32, 16), 256, 0, stream>>>(Ob, WoT, b_out, (float*)d_out);
}